// Round 7
// baseline (611.113 us; speedup 1.0000x reference)
//
#include <hip/hip_runtime.h>

#define D_MODEL 1024
#define D_STATE 16
#define DT_RANK 64
#define BATCH 2
#define SEQLEN 4096
#define NROWS (BATCH * SEQLEN)           // 8192
#define E_DIM 96
#define CH 32
#define NCH (SEQLEN / CH)                // 128

typedef short bf16x8 __attribute__((ext_vector_type(8)));
typedef float f32x4 __attribute__((ext_vector_type(4)));

// ---------------------------------------------------------------------------
// k_prep: Wx (96x1024 fp32) -> Wxbf (bf16 RNE, same layout)
//         W2 (1024x64)      -> W2T (64x1024 fp32)
// ---------------------------------------------------------------------------
__global__ __launch_bounds__(256)
void k_prep(const float* __restrict__ Wx, const float* __restrict__ W2,
            unsigned short* __restrict__ Wxbf, float* __restrict__ W2T) {
  const int bid = blockIdx.x;
  if (bid < 384) {                       // 96*1024 = 98304
    const int idx = bid * 256 + threadIdx.x;
    unsigned int u = __float_as_uint(Wx[idx]);
    u = (u + 0x7fffu + ((u >> 16) & 1u)) >> 16;   // RNE
    Wxbf[idx] = (unsigned short)u;
  } else {                               // 64*1024 = 65536
    const int idx = (bid - 384) * 256 + threadIdx.x;
    const int r = idx >> 10;
    const int d = idx & 1023;
    W2T[idx] = W2[(size_t)d * DT_RANK + r];
  }
}

// ---------------------------------------------------------------------------
// Kernel 1: dtBC = x @ Wx^T via bf16 MFMA 16x16x32, LDS-staged operands.
// Block: 256 thr (4 waves), M-tile 64, KSPLIT=4 (K=256/block).
// Rows padded to 72 bf16 (144B): aligned b128 reads, 2-way conflicts (free).
// D layout: row=(l>>4)*4+i, col=l&15  [m89-verified]
// ---------------------------------------------------------------------------
#define KSPLIT 4
#define KSEG (D_MODEL / KSPLIT)          // 256

__global__ __launch_bounds__(256)
void k_gemm1(const float* __restrict__ x, const unsigned short* __restrict__ Wxbf,
             float* __restrict__ parts) {
  __shared__ unsigned short sXb[64][72];   // 9.2 KB
  __shared__ unsigned short sWb[96][72];   // 13.8 KB
  const int tid = threadIdx.x;
  const int lane = tid & 63, w = tid >> 6;
  const int r = lane & 15, kq = lane >> 4;
  const int m0 = blockIdx.x * 64;
  const int ks0 = blockIdx.y * KSEG;

  f32x4 acc[6];
  #pragma unroll
  for (int j = 0; j < 6; ++j) acc[j] = (f32x4){0.f, 0.f, 0.f, 0.f};

  for (int kt = 0; kt < KSEG; kt += 64) {
    #pragma unroll
    for (int s = 0; s < 4; ++s) {
      const int f = s * 256 + tid;
      const int row = f >> 4, k4 = f & 15;
      const float4 v = *reinterpret_cast<const float4*>(
          &x[(size_t)(m0 + row) * D_MODEL + ks0 + kt + k4 * 4]);
      unsigned int u0, u1;
      asm("v_cvt_pk_bf16_f32 %0, %1, %2" : "=v"(u0) : "v"(v.x), "v"(v.y));
      asm("v_cvt_pk_bf16_f32 %0, %1, %2" : "=v"(u1) : "v"(v.z), "v"(v.w));
      *reinterpret_cast<uint2*>(&sXb[row][k4 * 4]) = make_uint2(u0, u1);
    }
    #pragma unroll
    for (int s = 0; s < 3; ++s) {
      const int f = s * 256 + tid;
      const int e = f >> 3, k8 = f & 7;
      *reinterpret_cast<uint4*>(&sWb[e][k8 * 8]) =
          *reinterpret_cast<const uint4*>(
              &Wxbf[(size_t)e * D_MODEL + ks0 + kt + k8 * 8]);
    }
    __syncthreads();
    #pragma unroll
    for (int ks = 0; ks < 2; ++ks) {
      const bf16x8 af = *reinterpret_cast<const bf16x8*>(
          &sXb[w * 16 + r][ks * 32 + kq * 8]);
      #pragma unroll
      for (int j = 0; j < 6; ++j) {
        const bf16x8 bf = *reinterpret_cast<const bf16x8*>(
            &sWb[j * 16 + r][ks * 32 + kq * 8]);
        acc[j] = __builtin_amdgcn_mfma_f32_16x16x32_bf16(af, bf, acc[j], 0, 0, 0);
      }
    }
    __syncthreads();
  }
  float* op = parts + (size_t)blockIdx.y * (NROWS * E_DIM);
  #pragma unroll
  for (int j = 0; j < 6; ++j)
    #pragma unroll
    for (int i = 0; i < 4; ++i)
      op[(size_t)(m0 + w * 16 + kq * 4 + i) * E_DIM + j * 16 + r] = acc[j][i];
}

// Sum KSPLIT partials -> dtBC.
__global__ __launch_bounds__(256)
void k_reduce(const float* __restrict__ parts, float* __restrict__ dtBC) {
  const int i = blockIdx.x * 256 + threadIdx.x;
  const float4* p = reinterpret_cast<const float4*>(parts);
  float4 a = p[i];
  #pragma unroll
  for (int s = 1; s < KSPLIT; ++s) {
    const float4 b = p[(size_t)s * (NROWS * E_DIM / 4) + i];
    a.x += b.x; a.y += b.y; a.z += b.z; a.w += b.w;
  }
  reinterpret_cast<float4*>(dtBC)[i] = a;
}

// ---------------------------------------------------------------------------
// Kernel 2: dt[m][d] = softplus(sum_r dtBC[m][r] * W2T[r][d] + b2[d])
// ---------------------------------------------------------------------------
#define G2_ROWS 32

__global__ __launch_bounds__(256)
void k_dt(const float* __restrict__ dtBC, const float* __restrict__ W2T,
          const float* __restrict__ b2, float* __restrict__ dt) {
  const int d = blockIdx.x * 256 + threadIdx.x;
  const int m0 = blockIdx.y * G2_ROWS;
  const float bias = b2[d];
  float acc[G2_ROWS];
  #pragma unroll
  for (int i = 0; i < G2_ROWS; ++i) acc[i] = bias;

  for (int r = 0; r < DT_RANK; ++r) {
    const float w = W2T[(size_t)r * D_MODEL + d];
    #pragma unroll
    for (int i = 0; i < G2_ROWS; ++i)
      acc[i] = fmaf(dtBC[(size_t)(m0 + i) * E_DIM + r], w, acc[i]);
  }
  #pragma unroll
  for (int i = 0; i < G2_ROWS; ++i) {
    const float a = acc[i];
    const float sp = (a > 15.f) ? a : __logf(1.f + __expf(a));
    dt[(size_t)(m0 + i) * D_MODEL + d] = sp;
  }
}

// ---------------------------------------------------------------------------
// Phase A: per-chunk transfer (P = prod dA, U = folded input sum).
// Scalar-only 2-deep load pipeline; __launch_bounds__ caps VGPR at 128.
// Layout of P/U/hst: [b][c][n][d] (d-coalesced).
// ---------------------------------------------------------------------------
__global__ __launch_bounds__(256, 4)
void k_scanA(const float* __restrict__ dt, const float* __restrict__ x,
             const float* __restrict__ dtBC, const float* __restrict__ A_log,
             float* __restrict__ P, float* __restrict__ U) {
  const int d = blockIdx.x * 256 + threadIdx.x;
  const int c = blockIdx.y;
  const int b = blockIdx.z;
  const int t0 = c * CH;

  __shared__ float sB[CH][D_STATE];
  for (int idx = threadIdx.x; idx < CH * D_STATE; idx += 256) {
    const int t = idx >> 4, n = idx & 15;
    sB[t][n] = dtBC[(size_t)(b * SEQLEN + t0 + t) * E_DIM + DT_RANK + n];
  }
  __syncthreads();

  float Ar[D_STATE];
  #pragma unroll
  for (int q = 0; q < 4; ++q) {
    const float4 v = *reinterpret_cast<const float4*>(
        &A_log[(size_t)d * D_STATE + q * 4]);
    Ar[q * 4 + 0] = -__expf(v.x); Ar[q * 4 + 1] = -__expf(v.y);
    Ar[q * 4 + 2] = -__expf(v.z); Ar[q * 4 + 3] = -__expf(v.w);
  }

  float Pr[D_STATE], Ur[D_STATE];
  #pragma unroll
  for (int n = 0; n < D_STATE; ++n) { Pr[n] = 1.f; Ur[n] = 0.f; }

  const float* dtp = dt + (size_t)(b * SEQLEN + t0) * D_MODEL + d;
  const float* xp  = x  + (size_t)(b * SEQLEN + t0) * D_MODEL + d;

  float d0 = dtp[0],          x0 = xp[0];
  float d1 = dtp[D_MODEL],    x1 = xp[D_MODEL];
  #pragma unroll
  for (int t = 0; t < CH; ++t) {
    float d2 = 0.f, x2 = 0.f;
    if (t + 2 < CH) {
      d2 = dtp[(size_t)(t + 2) * D_MODEL];
      x2 = xp[(size_t)(t + 2) * D_MODEL];
    }
    const float z = d0 * x0;
    #pragma unroll
    for (int n = 0; n < D_STATE; ++n) {
      const float e = __expf(d0 * Ar[n]);
      Ur[n] = fmaf(e, Ur[n], z * sB[t][n]);
      Pr[n] *= e;
    }
    d0 = d1; x0 = x1; d1 = d2; x1 = x2;
  }
  const size_t base = (size_t)(b * NCH + c) * (D_STATE * D_MODEL) + d;
  #pragma unroll
  for (int n = 0; n < D_STATE; ++n) {
    P[base + (size_t)n * D_MODEL] = Pr[n];
    U[base + (size_t)n * D_MODEL] = Ur[n];
  }
}

// ---------------------------------------------------------------------------
// Phase B: inter-chunk scan, batch-8 prefetch.
// ---------------------------------------------------------------------------
__global__ __launch_bounds__(256)
void k_scanB(const float* __restrict__ P, const float* __restrict__ U,
             float* __restrict__ hst) {
  const int idx = blockIdx.x * 256 + threadIdx.x;   // b*16384 + n*1024 + d
  const int b = idx >> 14;
  const int nd = idx & 16383;
  float h = 0.f;
  for (int c0 = 0; c0 < NCH; c0 += 8) {
    float p[8], u[8];
    #pragma unroll
    for (int i = 0; i < 8; ++i) {
      const size_t off = (size_t)(b * NCH + c0 + i) * (D_STATE * D_MODEL) + nd;
      p[i] = P[off]; u[i] = U[off];
    }
    #pragma unroll
    for (int i = 0; i < 8; ++i) {
      const size_t off = (size_t)(b * NCH + c0 + i) * (D_STATE * D_MODEL) + nd;
      hst[off] = h;
      h = fmaf(p[i], h, u[i]);
    }
  }
}

// ---------------------------------------------------------------------------
// Phase C: replay within chunk from hst, produce y. Same pipeline as A.
// ---------------------------------------------------------------------------
__global__ __launch_bounds__(256, 4)
void k_scanC(const float* __restrict__ dt, const float* __restrict__ x,
             const float* __restrict__ dtBC, const float* __restrict__ A_log,
             const float* __restrict__ Dp, const float* __restrict__ hst,
             float* __restrict__ y) {
  const int d = blockIdx.x * 256 + threadIdx.x;
  const int c = blockIdx.y;
  const int b = blockIdx.z;
  const int t0 = c * CH;

  __shared__ float sBC[CH][2 * D_STATE];   // [t][0..15]=B, [t][16..31]=C
  for (int idx = threadIdx.x; idx < CH * 2 * D_STATE; idx += 256) {
    const int t = idx >> 5, j = idx & 31;
    sBC[t][j] = dtBC[(size_t)(b * SEQLEN + t0 + t) * E_DIM + DT_RANK + j];
  }
  __syncthreads();

  float Ar[D_STATE];
  #pragma unroll
  for (int q = 0; q < 4; ++q) {
    const float4 v = *reinterpret_cast<const float4*>(
        &A_log[(size_t)d * D_STATE + q * 4]);
    Ar[q * 4 + 0] = -__expf(v.x); Ar[q * 4 + 1] = -__expf(v.y);
    Ar[q * 4 + 2] = -__expf(v.z); Ar[q * 4 + 3] = -__expf(v.w);
  }
  const float Dv = Dp[d];

  float h[D_STATE];
  const size_t hbase = (size_t)(b * NCH + c) * (D_STATE * D_MODEL) + d;
  #pragma unroll
  for (int n = 0; n < D_STATE; ++n) h[n] = hst[hbase + (size_t)n * D_MODEL];

  const float* dtp = dt + (size_t)(b * SEQLEN + t0) * D_MODEL + d;
  const float* xp  = x  + (size_t)(b * SEQLEN + t0) * D_MODEL + d;
  float* yp        = y  + (size_t)(b * SEQLEN + t0) * D_MODEL + d;

  float d0 = dtp[0],          x0 = xp[0];
  float d1 = dtp[D_MODEL],    x1 = xp[D_MODEL];
  #pragma unroll
  for (int t = 0; t < CH; ++t) {
    float d2 = 0.f, x2 = 0.f;
    if (t + 2 < CH) {
      d2 = dtp[(size_t)(t + 2) * D_MODEL];
      x2 = xp[(size_t)(t + 2) * D_MODEL];
    }
    const float z = d0 * x0;
    float acc = 0.f;
    #pragma unroll
    for (int n = 0; n < D_STATE; ++n) {
      const float e = __expf(d0 * Ar[n]);
      h[n] = fmaf(e, h[n], z * sBC[t][n]);
      acc = fmaf(h[n], sBC[t][D_STATE + n], acc);
    }
    yp[(size_t)t * D_MODEL] = fmaf(x0, Dv, acc);
    d0 = d1; x0 = x1; d1 = d2; x1 = x2;
  }
}

extern "C" void kernel_launch(void* const* d_in, const int* in_sizes, int n_in,
                              void* d_out, int out_size, void* d_ws, size_t ws_size,
                              hipStream_t stream) {
  const float* x     = (const float*)d_in[0];
  const float* A_log = (const float*)d_in[1];
  const float* Dp    = (const float*)d_in[2];
  const float* W2    = (const float*)d_in[3];   // dt_proj_w (1024,64)
  const float* b2    = (const float*)d_in[4];   // dt_proj_b (1024,)
  const float* Wx    = (const float*)d_in[5];   // x_to_dtBC_w (96,1024)
  float* out = (float*)d_out;

  float* ws = (float*)d_ws;
  // layout (floats):
  float* dtBC  = ws;                    //   786,432
  float* dtbuf = ws +   786432;         // 8,388,608
  float* P     = ws +  9175040;         // 4,194,304
  float* U     = ws + 13369344;         // 4,194,304
  float* hst   = ws + 17563648;         // 4,194,304  (end 21,757,952 = 87 MB)
  // aliases:
  float* parts = P;                     // 3,145,728 <= P+U span, dead post-reduce
  unsigned short* Wxbf = (unsigned short*)hst;   // dead before scanB writes hst
  float* W2T           = hst + 49152;            // dead before scanB writes hst

  hipLaunchKernelGGL(k_prep, dim3(640), dim3(256), 0, stream, Wx, W2, Wxbf, W2T);
  hipLaunchKernelGGL(k_gemm1, dim3(NROWS / 64, KSPLIT), dim3(256), 0, stream,
                     x, Wxbf, parts);
  hipLaunchKernelGGL(k_reduce, dim3(NROWS * E_DIM / 4 / 256), dim3(256), 0,
                     stream, parts, dtBC);
  hipLaunchKernelGGL(k_dt, dim3(D_MODEL / 256, NROWS / G2_ROWS), dim3(256), 0,
                     stream, dtBC, W2T, b2, dtbuf);
  hipLaunchKernelGGL(k_scanA, dim3(D_MODEL / 256, NCH, BATCH), dim3(256),
                     0, stream, dtbuf, x, dtBC, A_log, P, U);
  hipLaunchKernelGGL(k_scanB, dim3((BATCH * D_STATE * D_MODEL) / 256),
                     dim3(256), 0, stream, P, U, hst);
  hipLaunchKernelGGL(k_scanC, dim3(D_MODEL / 256, NCH, BATCH), dim3(256),
                     0, stream, dtbuf, x, dtBC, A_log, Dp, hst, out);
}

// Round 8
// 213.636 us; speedup vs baseline: 2.8605x; 2.8605x over previous
//
#include <hip/hip_runtime.h>

#define D_MODEL 1024
#define D_STATE 16
#define DT_RANK 64
#define BATCH 2
#define SEQLEN 4096
#define NROWS (BATCH * SEQLEN)           // 8192
#define E_DIM 96
#define CH 32
#define NCH (SEQLEN / CH)                // 128

typedef short bf16x8 __attribute__((ext_vector_type(8)));
typedef float f32x4 __attribute__((ext_vector_type(4)));

// ---------------------------------------------------------------------------
// k_prep: Wx (96x1024 fp32) -> Wxbf (bf16 RNE, same layout)
//         W2 (1024x64)      -> W2T (64x1024 fp32)
// ---------------------------------------------------------------------------
__global__ __launch_bounds__(256)
void k_prep(const float* __restrict__ Wx, const float* __restrict__ W2,
            unsigned short* __restrict__ Wxbf, float* __restrict__ W2T) {
  const int bid = blockIdx.x;
  if (bid < 384) {                       // 96*1024 = 98304
    const int idx = bid * 256 + threadIdx.x;
    unsigned int u = __float_as_uint(Wx[idx]);
    u = (u + 0x7fffu + ((u >> 16) & 1u)) >> 16;   // RNE
    Wxbf[idx] = (unsigned short)u;
  } else {                               // 64*1024 = 65536
    const int idx = (bid - 384) * 256 + threadIdx.x;
    const int r = idx >> 10;
    const int d = idx & 1023;
    W2T[idx] = W2[(size_t)d * DT_RANK + r];
  }
}

// ---------------------------------------------------------------------------
// Kernel 1: dtBC = x @ Wx^T via bf16 MFMA 16x16x32, LDS-staged operands.
// (R6 version — proven ≤40µs.) Block: 4 waves, M-tile 64, KSPLIT=4.
// Rows padded to 72 bf16 (144B): aligned b128 reads, 2-way conflicts (free).
// D layout: row=(l>>4)*4+i, col=l&15  [m89-verified]
// ---------------------------------------------------------------------------
#define KSPLIT 4
#define KSEG (D_MODEL / KSPLIT)          // 256

__global__ __launch_bounds__(256)
void k_gemm1(const float* __restrict__ x, const unsigned short* __restrict__ Wxbf,
             float* __restrict__ parts) {
  __shared__ unsigned short sXb[64][72];   // 9.2 KB
  __shared__ unsigned short sWb[96][72];   // 13.8 KB
  const int tid = threadIdx.x;
  const int lane = tid & 63, w = tid >> 6;
  const int r = lane & 15, kq = lane >> 4;
  const int m0 = blockIdx.x * 64;
  const int ks0 = blockIdx.y * KSEG;

  f32x4 acc[6];
  #pragma unroll
  for (int j = 0; j < 6; ++j) acc[j] = (f32x4){0.f, 0.f, 0.f, 0.f};

  for (int kt = 0; kt < KSEG; kt += 64) {
    #pragma unroll
    for (int s = 0; s < 4; ++s) {
      const int f = s * 256 + tid;
      const int row = f >> 4, k4 = f & 15;
      const float4 v = *reinterpret_cast<const float4*>(
          &x[(size_t)(m0 + row) * D_MODEL + ks0 + kt + k4 * 4]);
      unsigned int u0, u1;
      asm("v_cvt_pk_bf16_f32 %0, %1, %2" : "=v"(u0) : "v"(v.x), "v"(v.y));
      asm("v_cvt_pk_bf16_f32 %0, %1, %2" : "=v"(u1) : "v"(v.z), "v"(v.w));
      *reinterpret_cast<uint2*>(&sXb[row][k4 * 4]) = make_uint2(u0, u1);
    }
    #pragma unroll
    for (int s = 0; s < 3; ++s) {
      const int f = s * 256 + tid;
      const int e = f >> 3, k8 = f & 7;
      *reinterpret_cast<uint4*>(&sWb[e][k8 * 8]) =
          *reinterpret_cast<const uint4*>(
              &Wxbf[(size_t)e * D_MODEL + ks0 + kt + k8 * 8]);
    }
    __syncthreads();
    #pragma unroll
    for (int ks = 0; ks < 2; ++ks) {
      const bf16x8 af = *reinterpret_cast<const bf16x8*>(
          &sXb[w * 16 + r][ks * 32 + kq * 8]);
      #pragma unroll
      for (int j = 0; j < 6; ++j) {
        const bf16x8 bf = *reinterpret_cast<const bf16x8*>(
            &sWb[j * 16 + r][ks * 32 + kq * 8]);
        acc[j] = __builtin_amdgcn_mfma_f32_16x16x32_bf16(af, bf, acc[j], 0, 0, 0);
      }
    }
    __syncthreads();
  }
  float* op = parts + (size_t)blockIdx.y * (NROWS * E_DIM);
  #pragma unroll
  for (int j = 0; j < 6; ++j)
    #pragma unroll
    for (int i = 0; i < 4; ++i)
      op[(size_t)(m0 + w * 16 + kq * 4 + i) * E_DIM + j * 16 + r] = acc[j][i];
}

// Sum KSPLIT partials -> dtBC.
__global__ __launch_bounds__(256)
void k_reduce(const float* __restrict__ parts, float* __restrict__ dtBC) {
  const int i = blockIdx.x * 256 + threadIdx.x;
  const float4* p = reinterpret_cast<const float4*>(parts);
  float4 a = p[i];
  #pragma unroll
  for (int s = 1; s < KSPLIT; ++s) {
    const float4 b = p[(size_t)s * (NROWS * E_DIM / 4) + i];
    a.x += b.x; a.y += b.y; a.z += b.z; a.w += b.w;
  }
  reinterpret_cast<float4*>(dtBC)[i] = a;
}

// ---------------------------------------------------------------------------
// Kernel 2: dt[m][d] = softplus(sum_r dtBC[m][r] * W2T[r][d] + b2[d])
// ---------------------------------------------------------------------------
#define G2_ROWS 32

__global__ __launch_bounds__(256)
void k_dt(const float* __restrict__ dtBC, const float* __restrict__ W2T,
          const float* __restrict__ b2, float* __restrict__ dt) {
  const int d = blockIdx.x * 256 + threadIdx.x;
  const int m0 = blockIdx.y * G2_ROWS;
  const float bias = b2[d];
  float acc[G2_ROWS];
  #pragma unroll
  for (int i = 0; i < G2_ROWS; ++i) acc[i] = bias;

  for (int r = 0; r < DT_RANK; ++r) {
    const float w = W2T[(size_t)r * D_MODEL + d];
    #pragma unroll
    for (int i = 0; i < G2_ROWS; ++i)
      acc[i] = fmaf(dtBC[(size_t)(m0 + i) * E_DIM + r], w, acc[i]);
  }
  #pragma unroll
  for (int i = 0; i < G2_ROWS; ++i) {
    const float a = acc[i];
    const float sp = (a > 15.f) ? a : __logf(1.f + __expf(a));
    dt[(size_t)(m0 + i) * D_MODEL + d] = sp;
  }
}

// ---------------------------------------------------------------------------
// Phase A (R5 verbatim — measured ≤41µs): per-chunk transfer.
// Plain 1-deep load pipeline, no unroll pragma, no min-waves bound.
// Layout of P/U/hst: [b][c][n][d] (d-coalesced).
// ---------------------------------------------------------------------------
__global__ __launch_bounds__(256)
void k_scanA(const float* __restrict__ dt, const float* __restrict__ x,
             const float* __restrict__ dtBC, const float* __restrict__ A_log,
             float* __restrict__ P, float* __restrict__ U) {
  const int d = blockIdx.x * 256 + threadIdx.x;
  const int c = blockIdx.y;
  const int b = blockIdx.z;
  const int t0 = c * CH;

  __shared__ float sB[CH][D_STATE];
  for (int idx = threadIdx.x; idx < CH * D_STATE; idx += 256) {
    const int t = idx >> 4, n = idx & 15;
    sB[t][n] = dtBC[(size_t)(b * SEQLEN + t0 + t) * E_DIM + DT_RANK + n];
  }
  __syncthreads();

  float Ar[D_STATE];
  #pragma unroll
  for (int q = 0; q < 4; ++q) {
    const float4 v = *reinterpret_cast<const float4*>(
        &A_log[(size_t)d * D_STATE + q * 4]);
    Ar[q * 4 + 0] = -__expf(v.x); Ar[q * 4 + 1] = -__expf(v.y);
    Ar[q * 4 + 2] = -__expf(v.z); Ar[q * 4 + 3] = -__expf(v.w);
  }

  float Pr[D_STATE], Ur[D_STATE];
  #pragma unroll
  for (int n = 0; n < D_STATE; ++n) { Pr[n] = 1.f; Ur[n] = 0.f; }

  const float* dtp = dt + (size_t)(b * SEQLEN + t0) * D_MODEL + d;
  const float* xp  = x  + (size_t)(b * SEQLEN + t0) * D_MODEL + d;

  float dtv = dtp[0];
  float xv  = xp[0];
  for (int t = 0; t < CH; ++t) {
    float dtn = 0.f, xn = 0.f;
    if (t + 1 < CH) {
      dtn = dtp[(size_t)(t + 1) * D_MODEL];
      xn  = xp[(size_t)(t + 1) * D_MODEL];
    }
    const float z = dtv * xv;
    #pragma unroll
    for (int n = 0; n < D_STATE; ++n) {
      const float e = __expf(dtv * Ar[n]);
      Ur[n] = fmaf(e, Ur[n], z * sB[t][n]);
      Pr[n] *= e;
    }
    dtv = dtn; xv = xn;
  }
  const size_t base = (size_t)(b * NCH + c) * (D_STATE * D_MODEL) + d;
  #pragma unroll
  for (int n = 0; n < D_STATE; ++n) {
    P[base + (size_t)n * D_MODEL] = Pr[n];
    U[base + (size_t)n * D_MODEL] = Ur[n];
  }
}

// ---------------------------------------------------------------------------
// Phase B: inter-chunk scan, batch-8 prefetch.
// ---------------------------------------------------------------------------
__global__ __launch_bounds__(256)
void k_scanB(const float* __restrict__ P, const float* __restrict__ U,
             float* __restrict__ hst) {
  const int idx = blockIdx.x * 256 + threadIdx.x;   // b*16384 + n*1024 + d
  const int b = idx >> 14;
  const int nd = idx & 16383;
  float h = 0.f;
  for (int c0 = 0; c0 < NCH; c0 += 8) {
    float p[8], u[8];
    #pragma unroll
    for (int i = 0; i < 8; ++i) {
      const size_t off = (size_t)(b * NCH + c0 + i) * (D_STATE * D_MODEL) + nd;
      p[i] = P[off]; u[i] = U[off];
    }
    #pragma unroll
    for (int i = 0; i < 8; ++i) {
      const size_t off = (size_t)(b * NCH + c0 + i) * (D_STATE * D_MODEL) + nd;
      hst[off] = h;
      h = fmaf(p[i], h, u[i]);
    }
  }
}

// ---------------------------------------------------------------------------
// Phase C (R5 verbatim): replay within chunk from hst, produce y.
// ---------------------------------------------------------------------------
__global__ __launch_bounds__(256)
void k_scanC(const float* __restrict__ dt, const float* __restrict__ x,
             const float* __restrict__ dtBC, const float* __restrict__ A_log,
             const float* __restrict__ Dp, const float* __restrict__ hst,
             float* __restrict__ y) {
  const int d = blockIdx.x * 256 + threadIdx.x;
  const int c = blockIdx.y;
  const int b = blockIdx.z;
  const int t0 = c * CH;

  __shared__ float sBC[CH][2 * D_STATE];   // [t][0..15]=B, [t][16..31]=C
  for (int idx = threadIdx.x; idx < CH * 2 * D_STATE; idx += 256) {
    const int t = idx >> 5, j = idx & 31;
    sBC[t][j] = dtBC[(size_t)(b * SEQLEN + t0 + t) * E_DIM + DT_RANK + j];
  }
  __syncthreads();

  float Ar[D_STATE];
  #pragma unroll
  for (int q = 0; q < 4; ++q) {
    const float4 v = *reinterpret_cast<const float4*>(
        &A_log[(size_t)d * D_STATE + q * 4]);
    Ar[q * 4 + 0] = -__expf(v.x); Ar[q * 4 + 1] = -__expf(v.y);
    Ar[q * 4 + 2] = -__expf(v.z); Ar[q * 4 + 3] = -__expf(v.w);
  }
  const float Dv = Dp[d];

  float h[D_STATE];
  const size_t hbase = (size_t)(b * NCH + c) * (D_STATE * D_MODEL) + d;
  #pragma unroll
  for (int n = 0; n < D_STATE; ++n) h[n] = hst[hbase + (size_t)n * D_MODEL];

  const float* dtp = dt + (size_t)(b * SEQLEN + t0) * D_MODEL + d;
  const float* xp  = x  + (size_t)(b * SEQLEN + t0) * D_MODEL + d;
  float* yp        = y  + (size_t)(b * SEQLEN + t0) * D_MODEL + d;

  float dtv = dtp[0];
  float xv  = xp[0];
  for (int t = 0; t < CH; ++t) {
    float dtn = 0.f, xn = 0.f;
    if (t + 1 < CH) {
      dtn = dtp[(size_t)(t + 1) * D_MODEL];
      xn  = xp[(size_t)(t + 1) * D_MODEL];
    }
    const float z = dtv * xv;
    float acc = 0.f;
    #pragma unroll
    for (int n = 0; n < D_STATE; ++n) {
      const float e = __expf(dtv * Ar[n]);
      h[n] = fmaf(e, h[n], z * sBC[t][n]);
      acc = fmaf(h[n], sBC[t][D_STATE + n], acc);
    }
    yp[(size_t)t * D_MODEL] = fmaf(xv, Dv, acc);
    dtv = dtn; xv = xn;
  }
}

extern "C" void kernel_launch(void* const* d_in, const int* in_sizes, int n_in,
                              void* d_out, int out_size, void* d_ws, size_t ws_size,
                              hipStream_t stream) {
  const float* x     = (const float*)d_in[0];
  const float* A_log = (const float*)d_in[1];
  const float* Dp    = (const float*)d_in[2];
  const float* W2    = (const float*)d_in[3];   // dt_proj_w (1024,64)
  const float* b2    = (const float*)d_in[4];   // dt_proj_b (1024,)
  const float* Wx    = (const float*)d_in[5];   // x_to_dtBC_w (96,1024)
  float* out = (float*)d_out;

  float* ws = (float*)d_ws;
  // layout (floats):
  float* dtBC  = ws;                    //   786,432
  float* dtbuf = ws +   786432;         // 8,388,608
  float* P     = ws +  9175040;         // 4,194,304
  float* U     = ws + 13369344;         // 4,194,304
  float* hst   = ws + 17563648;         // 4,194,304  (end 21,757,952 = 87 MB)
  // aliases:
  float* parts = P;                     // 3,145,728 <= P+U span, dead post-reduce
  unsigned short* Wxbf = (unsigned short*)hst;   // dead before scanB writes hst
  float* W2T           = hst + 49152;            // dead before scanB writes hst

  hipLaunchKernelGGL(k_prep, dim3(640), dim3(256), 0, stream, Wx, W2, Wxbf, W2T);
  hipLaunchKernelGGL(k_gemm1, dim3(NROWS / 64, KSPLIT), dim3(256), 0, stream,
                     x, Wxbf, parts);
  hipLaunchKernelGGL(k_reduce, dim3(NROWS * E_DIM / 4 / 256), dim3(256), 0,
                     stream, parts, dtBC);
  hipLaunchKernelGGL(k_dt, dim3(D_MODEL / 256, NROWS / G2_ROWS), dim3(256), 0,
                     stream, dtBC, W2T, b2, dtbuf);
  hipLaunchKernelGGL(k_scanA, dim3(D_MODEL / 256, NCH, BATCH), dim3(256),
                     0, stream, dtbuf, x, dtBC, A_log, P, U);
  hipLaunchKernelGGL(k_scanB, dim3((BATCH * D_STATE * D_MODEL) / 256),
                     dim3(256), 0, stream, P, U, hst);
  hipLaunchKernelGGL(k_scanC, dim3(D_MODEL / 256, NCH, BATCH), dim3(256),
                     0, stream, dtbuf, x, dtBC, A_log, Dp, hst, out);
}

// Round 9
// 188.665 us; speedup vs baseline: 3.2391x; 1.1324x over previous
//
#include <hip/hip_runtime.h>

#define D_MODEL 1024
#define D_STATE 16
#define DT_RANK 64
#define BATCH 2
#define SEQLEN 4096
#define NROWS (BATCH * SEQLEN)           // 8192
#define E_DIM 96
#define CH 32
#define NCH (SEQLEN / CH)                // 128

typedef short bf16x8 __attribute__((ext_vector_type(8)));
typedef float f32x4 __attribute__((ext_vector_type(4)));

// ---------------------------------------------------------------------------
// k_prep: Wx (96x1024 fp32) -> Wxbf (bf16 RNE, same layout)
//         W2 (1024x64 fp32) -> W2bf (bf16 RNE, same layout)
// ---------------------------------------------------------------------------
__global__ __launch_bounds__(256)
void k_prep(const float* __restrict__ Wx, const float* __restrict__ W2,
            unsigned short* __restrict__ Wxbf, unsigned short* __restrict__ W2bf) {
  const int bid = blockIdx.x;
  if (bid < 384) {                       // 96*1024 = 98304
    const int idx = bid * 256 + threadIdx.x;
    unsigned int u = __float_as_uint(Wx[idx]);
    u = (u + 0x7fffu + ((u >> 16) & 1u)) >> 16;   // RNE
    Wxbf[idx] = (unsigned short)u;
  } else {                               // 1024*64 = 65536
    const int idx = (bid - 384) * 256 + threadIdx.x;
    unsigned int u = __float_as_uint(W2[idx]);
    u = (u + 0x7fffu + ((u >> 16) & 1u)) >> 16;   // RNE
    W2bf[idx] = (unsigned short)u;
  }
}

// ---------------------------------------------------------------------------
// Kernel 1: dtBC = x @ Wx^T via bf16 MFMA 16x16x32, LDS-staged operands.
// Block: 4 waves, M-tile 64, KSPLIT=4. Rows padded to 72 bf16 (144B).
// D layout: row=(l>>4)*4+i, col=l&15  [m89-verified]
// ---------------------------------------------------------------------------
#define KSPLIT 4
#define KSEG (D_MODEL / KSPLIT)          // 256

__global__ __launch_bounds__(256)
void k_gemm1(const float* __restrict__ x, const unsigned short* __restrict__ Wxbf,
             float* __restrict__ parts) {
  __shared__ unsigned short sXb[64][72];   // 9.2 KB
  __shared__ unsigned short sWb[96][72];   // 13.8 KB
  const int tid = threadIdx.x;
  const int lane = tid & 63, w = tid >> 6;
  const int r = lane & 15, kq = lane >> 4;
  const int m0 = blockIdx.x * 64;
  const int ks0 = blockIdx.y * KSEG;

  f32x4 acc[6];
  #pragma unroll
  for (int j = 0; j < 6; ++j) acc[j] = (f32x4){0.f, 0.f, 0.f, 0.f};

  for (int kt = 0; kt < KSEG; kt += 64) {
    #pragma unroll
    for (int s = 0; s < 4; ++s) {
      const int f = s * 256 + tid;
      const int row = f >> 4, k4 = f & 15;
      const float4 v = *reinterpret_cast<const float4*>(
          &x[(size_t)(m0 + row) * D_MODEL + ks0 + kt + k4 * 4]);
      unsigned int u0, u1;
      asm("v_cvt_pk_bf16_f32 %0, %1, %2" : "=v"(u0) : "v"(v.x), "v"(v.y));
      asm("v_cvt_pk_bf16_f32 %0, %1, %2" : "=v"(u1) : "v"(v.z), "v"(v.w));
      *reinterpret_cast<uint2*>(&sXb[row][k4 * 4]) = make_uint2(u0, u1);
    }
    #pragma unroll
    for (int s = 0; s < 3; ++s) {
      const int f = s * 256 + tid;
      const int e = f >> 3, k8 = f & 7;
      *reinterpret_cast<uint4*>(&sWb[e][k8 * 8]) =
          *reinterpret_cast<const uint4*>(
              &Wxbf[(size_t)e * D_MODEL + ks0 + kt + k8 * 8]);
    }
    __syncthreads();
    #pragma unroll
    for (int ks = 0; ks < 2; ++ks) {
      const bf16x8 af = *reinterpret_cast<const bf16x8*>(
          &sXb[w * 16 + r][ks * 32 + kq * 8]);
      #pragma unroll
      for (int j = 0; j < 6; ++j) {
        const bf16x8 bf = *reinterpret_cast<const bf16x8*>(
            &sWb[j * 16 + r][ks * 32 + kq * 8]);
        acc[j] = __builtin_amdgcn_mfma_f32_16x16x32_bf16(af, bf, acc[j], 0, 0, 0);
      }
    }
    __syncthreads();
  }
  float* op = parts + (size_t)blockIdx.y * (NROWS * E_DIM);
  #pragma unroll
  for (int j = 0; j < 6; ++j)
    #pragma unroll
    for (int i = 0; i < 4; ++i)
      op[(size_t)(m0 + w * 16 + kq * 4 + i) * E_DIM + j * 16 + r] = acc[j][i];
}

// Sum KSPLIT partials -> dtBC (fp32); also emit dt_in_bf = bf16 of cols 0..63.
__global__ __launch_bounds__(256)
void k_reduce(const float* __restrict__ parts, float* __restrict__ dtBC,
              unsigned short* __restrict__ dt_in_bf) {
  const int i = blockIdx.x * 256 + threadIdx.x;     // over 196608 float4
  const float4* p = reinterpret_cast<const float4*>(parts);
  float4 a = p[i];
  #pragma unroll
  for (int s = 1; s < KSPLIT; ++s) {
    const float4 b = p[(size_t)s * (NROWS * E_DIM / 4) + i];
    a.x += b.x; a.y += b.y; a.z += b.z; a.w += b.w;
  }
  reinterpret_cast<float4*>(dtBC)[i] = a;
  const int m = i / 24;                              // 24 float4 per row
  const int f4 = i - m * 24;
  if (f4 < 16) {                                     // cols 0..63 = dt_in
    unsigned int u0, u1;
    asm("v_cvt_pk_bf16_f32 %0, %1, %2" : "=v"(u0) : "v"(a.x), "v"(a.y));
    asm("v_cvt_pk_bf16_f32 %0, %1, %2" : "=v"(u1) : "v"(a.z), "v"(a.w));
    *reinterpret_cast<uint2*>(&dt_in_bf[(size_t)m * DT_RANK + f4 * 4]) =
        make_uint2(u0, u1);
  }
}

// ---------------------------------------------------------------------------
// Kernel 2 (MFMA): dt[m][d] = softplus(dt_in @ W2^T + b2), M=8192 N=1024 K=64.
// A-frag: dt_in_bf row (64 bf16, contiguous). B-frag: W2bf row d (64 bf16).
// Per block (4 waves): 64 rows x 64 cols; 8 MFMA/wave. Fused bias+softplus.
// ---------------------------------------------------------------------------
__global__ __launch_bounds__(256)
void k_dtm(const unsigned short* __restrict__ dt_in_bf,
           const unsigned short* __restrict__ W2bf,
           const float* __restrict__ b2, float* __restrict__ dt) {
  const int tid = threadIdx.x;
  const int lane = tid & 63, w = tid >> 6;
  const int r = lane & 15, kq = lane >> 4;
  const int m0 = blockIdx.x * 64 + w * 16;
  const int d0 = blockIdx.y * 64;

  f32x4 acc[4];
  #pragma unroll
  for (int j = 0; j < 4; ++j) acc[j] = (f32x4){0.f, 0.f, 0.f, 0.f};

  #pragma unroll
  for (int ks = 0; ks < 2; ++ks) {
    const bf16x8 af = *reinterpret_cast<const bf16x8*>(
        &dt_in_bf[(size_t)(m0 + r) * DT_RANK + ks * 32 + kq * 8]);
    #pragma unroll
    for (int j = 0; j < 4; ++j) {
      const bf16x8 bf = *reinterpret_cast<const bf16x8*>(
          &W2bf[(size_t)(d0 + j * 16 + r) * DT_RANK + ks * 32 + kq * 8]);
      acc[j] = __builtin_amdgcn_mfma_f32_16x16x32_bf16(af, bf, acc[j], 0, 0, 0);
    }
  }
  #pragma unroll
  for (int j = 0; j < 4; ++j) {
    const float bias = b2[d0 + j * 16 + r];
    #pragma unroll
    for (int i = 0; i < 4; ++i) {
      const float a = acc[j][i] + bias;
      const float sp = (a > 15.f) ? a : __logf(1.f + __expf(a));
      dt[(size_t)(m0 + kq * 4 + i) * D_MODEL + d0 + j * 16 + r] = sp;
    }
  }
}

// ---------------------------------------------------------------------------
// Phase A (proven ≤41µs): per-chunk transfer. Plain 1-deep pipeline.
// Layout of P/U/hst: [b][c][n][d] (d-coalesced).
// ---------------------------------------------------------------------------
__global__ __launch_bounds__(256)
void k_scanA(const float* __restrict__ dt, const float* __restrict__ x,
             const float* __restrict__ dtBC, const float* __restrict__ A_log,
             float* __restrict__ P, float* __restrict__ U) {
  const int d = blockIdx.x * 256 + threadIdx.x;
  const int c = blockIdx.y;
  const int b = blockIdx.z;
  const int t0 = c * CH;

  __shared__ float sB[CH][D_STATE];
  for (int idx = threadIdx.x; idx < CH * D_STATE; idx += 256) {
    const int t = idx >> 4, n = idx & 15;
    sB[t][n] = dtBC[(size_t)(b * SEQLEN + t0 + t) * E_DIM + DT_RANK + n];
  }
  __syncthreads();

  float Ar[D_STATE];
  #pragma unroll
  for (int q = 0; q < 4; ++q) {
    const float4 v = *reinterpret_cast<const float4*>(
        &A_log[(size_t)d * D_STATE + q * 4]);
    Ar[q * 4 + 0] = -__expf(v.x); Ar[q * 4 + 1] = -__expf(v.y);
    Ar[q * 4 + 2] = -__expf(v.z); Ar[q * 4 + 3] = -__expf(v.w);
  }

  float Pr[D_STATE], Ur[D_STATE];
  #pragma unroll
  for (int n = 0; n < D_STATE; ++n) { Pr[n] = 1.f; Ur[n] = 0.f; }

  const float* dtp = dt + (size_t)(b * SEQLEN + t0) * D_MODEL + d;
  const float* xp  = x  + (size_t)(b * SEQLEN + t0) * D_MODEL + d;

  float dtv = dtp[0];
  float xv  = xp[0];
  for (int t = 0; t < CH; ++t) {
    float dtn = 0.f, xn = 0.f;
    if (t + 1 < CH) {
      dtn = dtp[(size_t)(t + 1) * D_MODEL];
      xn  = xp[(size_t)(t + 1) * D_MODEL];
    }
    const float z = dtv * xv;
    #pragma unroll
    for (int n = 0; n < D_STATE; ++n) {
      const float e = __expf(dtv * Ar[n]);
      Ur[n] = fmaf(e, Ur[n], z * sB[t][n]);
      Pr[n] *= e;
    }
    dtv = dtn; xv = xn;
  }
  const size_t base = (size_t)(b * NCH + c) * (D_STATE * D_MODEL) + d;
  #pragma unroll
  for (int n = 0; n < D_STATE; ++n) {
    P[base + (size_t)n * D_MODEL] = Pr[n];
    U[base + (size_t)n * D_MODEL] = Ur[n];
  }
}

// ---------------------------------------------------------------------------
// Phase B: inter-chunk scan, batch-8 prefetch.
// ---------------------------------------------------------------------------
__global__ __launch_bounds__(256)
void k_scanB(const float* __restrict__ P, const float* __restrict__ U,
             float* __restrict__ hst) {
  const int idx = blockIdx.x * 256 + threadIdx.x;   // b*16384 + n*1024 + d
  const int b = idx >> 14;
  const int nd = idx & 16383;
  float h = 0.f;
  for (int c0 = 0; c0 < NCH; c0 += 8) {
    float p[8], u[8];
    #pragma unroll
    for (int i = 0; i < 8; ++i) {
      const size_t off = (size_t)(b * NCH + c0 + i) * (D_STATE * D_MODEL) + nd;
      p[i] = P[off]; u[i] = U[off];
    }
    #pragma unroll
    for (int i = 0; i < 8; ++i) {
      const size_t off = (size_t)(b * NCH + c0 + i) * (D_STATE * D_MODEL) + nd;
      hst[off] = h;
      h = fmaf(p[i], h, u[i]);
    }
  }
}

// ---------------------------------------------------------------------------
// Phase C: replay within chunk from hst, produce y.
// ---------------------------------------------------------------------------
__global__ __launch_bounds__(256)
void k_scanC(const float* __restrict__ dt, const float* __restrict__ x,
             const float* __restrict__ dtBC, const float* __restrict__ A_log,
             const float* __restrict__ Dp, const float* __restrict__ hst,
             float* __restrict__ y) {
  const int d = blockIdx.x * 256 + threadIdx.x;
  const int c = blockIdx.y;
  const int b = blockIdx.z;
  const int t0 = c * CH;

  __shared__ float sBC[CH][2 * D_STATE];   // [t][0..15]=B, [t][16..31]=C
  for (int idx = threadIdx.x; idx < CH * 2 * D_STATE; idx += 256) {
    const int t = idx >> 5, j = idx & 31;
    sBC[t][j] = dtBC[(size_t)(b * SEQLEN + t0 + t) * E_DIM + DT_RANK + j];
  }
  __syncthreads();

  float Ar[D_STATE];
  #pragma unroll
  for (int q = 0; q < 4; ++q) {
    const float4 v = *reinterpret_cast<const float4*>(
        &A_log[(size_t)d * D_STATE + q * 4]);
    Ar[q * 4 + 0] = -__expf(v.x); Ar[q * 4 + 1] = -__expf(v.y);
    Ar[q * 4 + 2] = -__expf(v.z); Ar[q * 4 + 3] = -__expf(v.w);
  }
  const float Dv = Dp[d];

  float h[D_STATE];
  const size_t hbase = (size_t)(b * NCH + c) * (D_STATE * D_MODEL) + d;
  #pragma unroll
  for (int n = 0; n < D_STATE; ++n) h[n] = hst[hbase + (size_t)n * D_MODEL];

  const float* dtp = dt + (size_t)(b * SEQLEN + t0) * D_MODEL + d;
  const float* xp  = x  + (size_t)(b * SEQLEN + t0) * D_MODEL + d;
  float* yp        = y  + (size_t)(b * SEQLEN + t0) * D_MODEL + d;

  float dtv = dtp[0];
  float xv  = xp[0];
  for (int t = 0; t < CH; ++t) {
    float dtn = 0.f, xn = 0.f;
    if (t + 1 < CH) {
      dtn = dtp[(size_t)(t + 1) * D_MODEL];
      xn  = xp[(size_t)(t + 1) * D_MODEL];
    }
    const float z = dtv * xv;
    float acc = 0.f;
    #pragma unroll
    for (int n = 0; n < D_STATE; ++n) {
      const float e = __expf(dtv * Ar[n]);
      h[n] = fmaf(e, h[n], z * sBC[t][n]);
      acc = fmaf(h[n], sBC[t][D_STATE + n], acc);
    }
    yp[(size_t)t * D_MODEL] = fmaf(xv, Dv, acc);
    dtv = dtn; xv = xn;
  }
}

extern "C" void kernel_launch(void* const* d_in, const int* in_sizes, int n_in,
                              void* d_out, int out_size, void* d_ws, size_t ws_size,
                              hipStream_t stream) {
  const float* x     = (const float*)d_in[0];
  const float* A_log = (const float*)d_in[1];
  const float* Dp    = (const float*)d_in[2];
  const float* W2    = (const float*)d_in[3];   // dt_proj_w (1024,64)
  const float* b2    = (const float*)d_in[4];   // dt_proj_b (1024,)
  const float* Wx    = (const float*)d_in[5];   // x_to_dtBC_w (96,1024)
  float* out = (float*)d_out;

  float* ws = (float*)d_ws;
  // layout (floats):
  float* dtBC  = ws;                    //   786,432
  float* dtbuf = ws +   786432;         // 8,388,608
  float* P     = ws +  9175040;         // 4,194,304
  float* U     = ws + 13369344;         // 4,194,304
  float* hst   = ws + 17563648;         // 4,194,304  (end 21,757,952 = 87 MB)
  // aliases:
  float* parts = P;                     // 3,145,728 <= P span, dead post-reduce
  unsigned short* Wxbf     = (unsigned short*)hst;             //  98,304 bf16
  unsigned short* W2bf     = (unsigned short*)(hst + 49152);   //  65,536 bf16
  unsigned short* dt_in_bf = (unsigned short*)(hst + 82944);   // 524,288 bf16
  // (all dead before k_scanB writes hst)

  hipLaunchKernelGGL(k_prep, dim3(640), dim3(256), 0, stream, Wx, W2, Wxbf, W2bf);
  hipLaunchKernelGGL(k_gemm1, dim3(NROWS / 64, KSPLIT), dim3(256), 0, stream,
                     x, Wxbf, parts);
  hipLaunchKernelGGL(k_reduce, dim3(NROWS * E_DIM / 4 / 256), dim3(256), 0,
                     stream, parts, dtBC, dt_in_bf);
  hipLaunchKernelGGL(k_dtm, dim3(NROWS / 64, D_MODEL / 64), dim3(256), 0,
                     stream, dt_in_bf, W2bf, b2, dtbuf);
  hipLaunchKernelGGL(k_scanA, dim3(D_MODEL / 256, NCH, BATCH), dim3(256),
                     0, stream, dtbuf, x, dtBC, A_log, P, U);
  hipLaunchKernelGGL(k_scanB, dim3((BATCH * D_STATE * D_MODEL) / 256),
                     dim3(256), 0, stream, P, U, hst);
  hipLaunchKernelGGL(k_scanC, dim3(D_MODEL / 256, NCH, BATCH), dim3(256),
                     0, stream, dtbuf, x, dtBC, A_log, Dp, hst, out);
}